// Round 9
// baseline (235.201 us; speedup 1.0000x reference)
//
#include <hip/hip_runtime.h>
#include <hip/hip_bf16.h>
#include <cstddef>

// 3-layer tanh RNN (B=8192, T=80, D=32, H=64), fused, MFMA, REGISTER-ONLY.
//
// KEY IDENTITY (K=16 MFMA): B-frag map  B[k=4*(lane>>4)+i][n=lane&15]
//                     and   C/D map     D[row=4*(lane>>4)+r][col=lane&15]
// are the SAME lane/slot mapping. So a 16x16 D-tile (pre-activation), after
// elementwise tanh + pairwise bf16 pack, IS the next GEMM's B-operand with
// k = j (row), n = batch (col). No transpose, no LDS, no barriers, no shuffles.
//
// One wave owns 16 batches end-to-end: all 3 layers x 80 steps in registers.
//   A = weights (VGPR-resident): K=16 frags wfragA16 (s16x4), plus one K=32
//       frag set for the x*Wih0 part (x's B-frag is loaded straight from global
//       in B-layout -- we control that layout, so K=32 is free there).
//   h_l state: 4 B-frags (s16x4) per layer, carried in registers across t.
// Grid: 512 blocks x 64 thr = 512 independent waves (B/16), ~2 waves/CU.
// No __syncthreads anywhere. x(t+1) prefetched one iteration ahead (its vmcnt
// wait lands a full iteration later -- no barrier ever drains it).
//
// Verified maps (R2-R8, end-to-end): 16x16x32: A[m=lane&15][k=8q+i],
// B[k=8q+i][n=lane&15], D[row=4q+r][col=lane&15]. K=16 uses the same family
// with 4-wide k-groups. tanh via exp2 (bias pre-scaled by 2*log2e), identical
// numerics to R2-R8 (absmax 0.015625 expected unchanged).

typedef __attribute__((ext_vector_type(8))) short s16x8;
typedef __attribute__((ext_vector_type(4))) short s16x4;
typedef __attribute__((ext_vector_type(4))) float fx4;

#define MFMA32(A, B, C) __builtin_amdgcn_mfma_f32_16x16x32_bf16((A), (B), (C), 0, 0, 0)
#define MFMA16(A, B, C) __builtin_amdgcn_mfma_f32_16x16x16bf16_1k((A), (B), (C), 0, 0, 0)

#if __has_builtin(__builtin_amdgcn_exp2f)
#define EXP2F(x) __builtin_amdgcn_exp2f(x)
#else
#define EXP2F(x) exp2f(x)
#endif
#if __has_builtin(__builtin_amdgcn_rcpf)
#define RCPF(x) __builtin_amdgcn_rcpf(x)
#else
#define RCPF(x) (1.0f / (x))
#endif

static constexpr float K2LOG2E = 2.8853900817779268f;  // 2*log2(e)

__device__ __forceinline__ short f2bf(float f) {  // RNE float->bf16 (weights, one-time)
  union { float f; unsigned u; } v; v.f = f;
  unsigned r = v.u + 0x7FFFu + ((v.u >> 16) & 1u);
  return (short)(r >> 16);
}
__device__ __forceinline__ float bf2f(short s) {
  union { unsigned u; float f; } v; v.u = ((unsigned)(unsigned short)s) << 16;
  return v.f;
}
__device__ __forceinline__ unsigned pk2bf(float a, float b) {  // v_cvt_pk_bf16_f32
  float2 t; t.x = a; t.y = b;
  union { __hip_bfloat162 h; unsigned u; } c;
  c.h = __float22bfloat162_rn(t);
  return c.u;
}

__device__ __forceinline__ s16x4 wfragA16(const float* W, int ncols, int row, int col0) {
  const float* p = W + row * ncols + col0;
  s16x4 r;
#pragma unroll
  for (int i = 0; i < 4; ++i) r[i] = f2bf(p[i]);
  return r;
}
__device__ __forceinline__ s16x8 wfragA32(const float* W, int ncols, int row, int col0) {
  const float* p = W + row * ncols + col0;
  s16x8 r;
#pragma unroll
  for (int i = 0; i < 8; ++i) r[i] = f2bf(p[i]);
  return r;
}

// tanh(acc + bias) (bias pre-scaled by 2*log2e) -> packed bf16 B-frag piece.
// Pack order (r0,r1),(r2,r3) matches B-frag slot order i=(0,1),(2,3).
__device__ __forceinline__ s16x4 tanh_pack(fx4 acc, const float* bs) {
  float h[4];
#pragma unroll
  for (int r = 0; r < 4; ++r) {
    float e = EXP2F(__builtin_fmaf(acc[r], K2LOG2E, bs[r]));
    h[r] = __builtin_fmaf(-2.f, RCPF(e + 1.f), 1.f);
  }
  union { unsigned u[2]; s16x4 v; } p;
  p.u[0] = pk2bf(h[0], h[1]);
  p.u[1] = pk2bf(h[2], h[3]);
  return p.v;
}

__global__ __launch_bounds__(64, 1) void rnn3_k16(
    const float* __restrict__ x,
    const float* __restrict__ Wih0, const float* __restrict__ Whh0,
    const float* __restrict__ bih0, const float* __restrict__ bhh0,
    const float* __restrict__ Wih1, const float* __restrict__ Whh1,
    const float* __restrict__ bih1, const float* __restrict__ bhh1,
    const float* __restrict__ Wih2, const float* __restrict__ Whh2,
    const float* __restrict__ bih2, const float* __restrict__ bhh2,
    const float* __restrict__ Wfc, const float* __restrict__ bfc,
    float* __restrict__ out)
{
  const int ln  = threadIdx.x & 63;
  const int Q   = ln >> 4;        // k-group / row-quad
  const int m15 = ln & 15;        // A: row m   |  B/D: col n (batch)
  const int bbase = (int)blockIdx.x * 16;

  // ---------------- weights, VGPR-resident ----------------
  // x-part of L0 at K=32 (x B-frag loaded directly in K=32 B-layout).
  s16x8 wx[4];
#pragma unroll
  for (int t4 = 0; t4 < 4; ++t4) wx[t4] = wfragA32(Wih0, 32, 16 * t4 + m15, 8 * Q);
  // All h contractions at K=16: frag [tile][kf], k in [16kf, 16kf+16).
  s16x4 wh0[4][4], wi1[4][4], wh1[4][4], wi2[4][4], wh2[4][4];
#pragma unroll
  for (int t4 = 0; t4 < 4; ++t4) {
    const int row = 16 * t4 + m15;
#pragma unroll
    for (int kf = 0; kf < 4; ++kf) {
      const int c = 16 * kf + 4 * Q;
      wh0[t4][kf] = wfragA16(Whh0, 64, row, c);
      wi1[t4][kf] = wfragA16(Wih1, 64, row, c);
      wh1[t4][kf] = wfragA16(Whh1, 64, row, c);
      wi2[t4][kf] = wfragA16(Wih2, 64, row, c);
      wh2[t4][kf] = wfragA16(Whh2, 64, row, c);
    }
  }

  // ---------------- biases pre-scaled; lane's j = 16*tile + 4*Q + r ----------
  float bs0[4][4], bs1[4][4], bs2[4][4];
#pragma unroll
  for (int t4 = 0; t4 < 4; ++t4)
#pragma unroll
    for (int r = 0; r < 4; ++r) {
      const int j = 16 * t4 + 4 * Q + r;
      bs0[t4][r] = (bih0[j] + bhh0[j]) * K2LOG2E;
      bs1[t4][r] = (bih1[j] + bhh1[j]) * K2LOG2E;
      bs2[t4][r] = (bih2[j] + bhh2[j]) * K2LOG2E;
    }

  // ---------------- state: h_l as 4 K=16 B-frags per layer (registers) ------
  const s16x4 z2 = {0, 0, 0, 0};
  s16x4 h0f[4] = {z2, z2, z2, z2};
  s16x4 h1f[4] = {z2, z2, z2, z2};
  s16x4 h2f[4] = {z2, z2, z2, z2};
  const fx4 z4 = {0.f, 0.f, 0.f, 0.f};

  // x source: lane reads x[bbase+m15][t][8Q .. 8Q+7] (K=32 B-frag layout)
  const float* xr = x + (size_t)(bbase + m15) * (80 * 32) + 8 * Q;
  fx4 xc0 = *(const fx4*)(xr);
  fx4 xc1 = *(const fx4*)(xr + 4);

  for (int t = 0; t < 80; ++t) {
    // pack x(t); prefetch x(t+1) (no barrier ever drains it)
    union { unsigned u[4]; s16x8 v; } xp;
    xp.u[0] = pk2bf(xc0[0], xc0[1]); xp.u[1] = pk2bf(xc0[2], xc0[3]);
    xp.u[2] = pk2bf(xc1[0], xc1[1]); xp.u[3] = pk2bf(xc1[2], xc1[3]);
    const int tn = (t < 79) ? t + 1 : 79;
    xc0 = *(const fx4*)(xr + tn * 32);
    xc1 = *(const fx4*)(xr + tn * 32 + 4);

    fx4 a[4];
    // ---------------- L0: h0(t) = tanh(Wih0 x + Whh0 h0) ----------------
#pragma unroll
    for (int t4 = 0; t4 < 4; ++t4) a[t4] = MFMA32(wx[t4], xp.v, z4);
#pragma unroll
    for (int kf = 0; kf < 4; ++kf)
#pragma unroll
      for (int t4 = 0; t4 < 4; ++t4) a[t4] = MFMA16(wh0[t4][kf], h0f[kf], a[t4]);
#pragma unroll
    for (int t4 = 0; t4 < 4; ++t4) h0f[t4] = tanh_pack(a[t4], bs0[t4]);  // D==B!

    // ---------------- L1: h1(t) = tanh(Wih1 h0(t) + Whh1 h1(t-1)) --------
#pragma unroll
    for (int t4 = 0; t4 < 4; ++t4) a[t4] = MFMA16(wi1[t4][0], h0f[0], z4);
#pragma unroll
    for (int kf = 1; kf < 4; ++kf)
#pragma unroll
      for (int t4 = 0; t4 < 4; ++t4) a[t4] = MFMA16(wi1[t4][kf], h0f[kf], a[t4]);
#pragma unroll
    for (int kf = 0; kf < 4; ++kf)
#pragma unroll
      for (int t4 = 0; t4 < 4; ++t4) a[t4] = MFMA16(wh1[t4][kf], h1f[kf], a[t4]);
#pragma unroll
    for (int t4 = 0; t4 < 4; ++t4) h1f[t4] = tanh_pack(a[t4], bs1[t4]);

    // ---------------- L2: h2(t) = tanh(Wih2 h1(t) + Whh2 h2(t-1)) --------
#pragma unroll
    for (int t4 = 0; t4 < 4; ++t4) a[t4] = MFMA16(wi2[t4][0], h1f[0], z4);
#pragma unroll
    for (int kf = 1; kf < 4; ++kf)
#pragma unroll
      for (int t4 = 0; t4 < 4; ++t4) a[t4] = MFMA16(wi2[t4][kf], h1f[kf], a[t4]);
#pragma unroll
    for (int kf = 0; kf < 4; ++kf)
#pragma unroll
      for (int t4 = 0; t4 < 4; ++t4) a[t4] = MFMA16(wh2[t4][kf], h2f[kf], a[t4]);
#pragma unroll
    for (int t4 = 0; t4 < 4; ++t4) h2f[t4] = tanh_pack(a[t4], bs2[t4]);
  }

  // ---------------- FC head: out[b] = Wfc . h2(79) + bfc ----------------
  // h2f[kf] holds h2[j = 16kf + 4Q + i][b = m15], i = 0..3.
  float sv = 0.f;
#pragma unroll
  for (int kf = 0; kf < 4; ++kf)
#pragma unroll
    for (int i = 0; i < 4; ++i)
      sv += bf2f(h2f[kf][i]) * Wfc[16 * kf + 4 * Q + i];
  sv += __shfl_xor(sv, 16, 64);
  sv += __shfl_xor(sv, 32, 64);
  if (ln < 16) out[bbase + ln] = sv + bfc[0];
}

extern "C" void kernel_launch(void* const* d_in, const int* in_sizes, int n_in,
                              void* d_out, int out_size, void* d_ws, size_t ws_size,
                              hipStream_t stream) {
  const float* x    = (const float*)d_in[0];
  const float* Wih0 = (const float*)d_in[1];
  const float* Whh0 = (const float*)d_in[2];
  const float* bih0 = (const float*)d_in[3];
  const float* bhh0 = (const float*)d_in[4];
  const float* Wih1 = (const float*)d_in[5];
  const float* Whh1 = (const float*)d_in[6];
  const float* bih1 = (const float*)d_in[7];
  const float* bhh1 = (const float*)d_in[8];
  const float* Wih2 = (const float*)d_in[9];
  const float* Whh2 = (const float*)d_in[10];
  const float* bih2 = (const float*)d_in[11];
  const float* bhh2 = (const float*)d_in[12];
  const float* Wfc  = (const float*)d_in[13];
  const float* bfc  = (const float*)d_in[14];

  // 512 blocks x 64 thr = 512 fully independent waves (16 batch rows each).
  // No LDS, no barriers: the D->B layout identity makes the recurrence
  // register-resident end-to-end.
  rnn3_k16<<<dim3(512), dim3(64), 0, stream>>>(
      x, Wih0, Whh0, bih0, bhh0, Wih1, Whh1, bih1, bhh1,
      Wih2, Whh2, bih2, bhh2, Wfc, bfc, (float*)d_out);
}